// Round 3
// baseline (1804.053 us; speedup 1.0000x reference)
//
#include <hip/hip_runtime.h>
#include <hip/hip_bf16.h>
#include <cstdint>
#include <cstddef>

#define USER_N 40000
#define ITEM_N 40000
#define NN     80000
#define DD     128
#define KK     16
#define EE     1600000

typedef __attribute__((ext_vector_type(8))) short bf16x8;
typedef __attribute__((ext_vector_type(4))) float f32x4;
typedef unsigned short ushort_t;
typedef unsigned int   uint32;

static __device__ __forceinline__ ushort_t f2bf(float x){
  __hip_bfloat16 h = __float2bfloat16(x);
  return *reinterpret_cast<ushort_t*>(&h);
}
static __device__ __forceinline__ float bflo(uint32 u){ return __uint_as_float(u << 16); }
static __device__ __forceinline__ float bfhi(uint32 u){ return __uint_as_float(u & 0xffff0000u); }
static __device__ __forceinline__ float bf2f(ushort_t u){ return __uint_as_float(((uint32)u) << 16); }

// ---------------- init: e_bf = bf16(concat(user,item)); total(d_out) = concat ----------------
__global__ void init_e_total(const float* __restrict__ user_emb, const float* __restrict__ item_emb,
                             ushort_t* __restrict__ e_bf, float* __restrict__ total){
  int idx = blockIdx.x*blockDim.x + threadIdx.x;           // float4 index
  const int n4 = NN*DD/4;
  if (idx >= n4) return;
  const int u4 = USER_N*DD/4;
  float4 v = (idx < u4) ? ((const float4*)user_emb)[idx] : ((const float4*)item_emb)[idx - u4];
  ((float4*)total)[idx] = v;
  ushort4 b; b.x = f2bf(v.x); b.y = f2bf(v.y); b.z = f2bf(v.z); b.w = f2bf(v.w);
  ((ushort4*)e_bf)[idx] = b;
}

// ---------------- weights -> bf16 ----------------
// layout: u_in (3*16384) | i_in (3*16384) | u_out (16384) | i_out (16384)
__global__ void cvt_weights(const float* __restrict__ u_in_w, const float* __restrict__ i_in_w,
                            const float* __restrict__ u_out_w, const float* __restrict__ i_out_w,
                            ushort_t* __restrict__ wbf){
  int i = blockIdx.x*256 + threadIdx.x;   // 512 blocks x 256 = 131072
  float v;
  if      (i < 49152)  v = u_in_w[i];
  else if (i < 98304)  v = i_in_w[i - 49152];
  else if (i < 114688) v = u_out_w[i - 98304];
  else                 v = i_out_w[i - 114688];
  wbf[i] = f2bf(v);
}

// ---------------- CSR build ----------------
__global__ void hist_rows(const int* __restrict__ rows, int* __restrict__ counts){
  int i = blockIdx.x*blockDim.x + threadIdx.x;
  if (i < EE) atomicAdd(&counts[rows[i]], 1);
}

__global__ void block_sum(const int* __restrict__ counts, int* __restrict__ bsum){
  __shared__ int s[256];
  int i = blockIdx.x*256 + threadIdx.x;
  s[threadIdx.x] = (i < NN) ? counts[i] : 0;
  __syncthreads();
  for (int o = 128; o > 0; o >>= 1){
    if (threadIdx.x < o) s[threadIdx.x] += s[threadIdx.x + o];
    __syncthreads();
  }
  if (threadIdx.x == 0) bsum[blockIdx.x] = s[0];
}

__global__ void scan_bsum(const int* __restrict__ bsum, int* __restrict__ bpre,
                          int* __restrict__ row_ptr){
  __shared__ int s[512];
  int v = (threadIdx.x < 313) ? bsum[threadIdx.x] : 0;
  s[threadIdx.x] = v;
  __syncthreads();
  for (int o = 1; o < 512; o <<= 1){
    int t = (threadIdx.x >= o) ? s[threadIdx.x - o] : 0;
    __syncthreads();
    s[threadIdx.x] += t;
    __syncthreads();
  }
  if (threadIdx.x < 313) bpre[threadIdx.x] = s[threadIdx.x] - v;
  if (threadIdx.x == 312) row_ptr[NN] = s[312];
}

__global__ void block_scan(const int* __restrict__ counts, const int* __restrict__ bpre,
                           int* __restrict__ row_ptr, int* __restrict__ cursor){
  __shared__ int s[256];
  int i = blockIdx.x*256 + threadIdx.x;
  int v = (i < NN) ? counts[i] : 0;
  s[threadIdx.x] = v;
  __syncthreads();
  for (int o = 1; o < 256; o <<= 1){
    int t = (threadIdx.x >= o) ? s[threadIdx.x - o] : 0;
    __syncthreads();
    s[threadIdx.x] += t;
    __syncthreads();
  }
  if (i < NN){
    int ex = bpre[blockIdx.x] + s[threadIdx.x] - v;
    row_ptr[i] = ex; cursor[i] = ex;
  }
}

// packed (col, val) single 8B store per edge
__global__ void scatter_edges(const int* __restrict__ rows, const int* __restrict__ cols,
                              const float* __restrict__ vals, int* __restrict__ cursor,
                              uint2* __restrict__ csr){
  int i = blockIdx.x*blockDim.x + threadIdx.x;
  if (i >= EE) return;
  int r = rows[i];
  int p = atomicAdd(&cursor[r], 1);
  csr[p] = make_uint2((uint32)cols[i], __float_as_uint(vals[i]));
}

// ---------------- SpMM: one wave per row; bf16 gather (256B/row), bf16 output ----------
__global__ __launch_bounds__(256) void spmm_kernel(const int* __restrict__ row_ptr,
    const uint2* __restrict__ csr, const ushort_t* __restrict__ e_bf,
    ushort_t* __restrict__ tmp_bf){
  int wid  = (blockIdx.x*blockDim.x + threadIdx.x) >> 6;
  int lane = threadIdx.x & 63;
  if (wid >= NN) return;
  int s = row_ptr[wid], t = row_ptr[wid+1];
  const uint32* E = (const uint32*)e_bf;   // 2 bf16 per uint
  float ax = 0.f, ay = 0.f;
  int e = s;
  for (; e + 1 < t; e += 2){
    uint2 c0 = csr[e], c1 = csr[e+1];
    float v0 = __uint_as_float(c0.y), v1 = __uint_as_float(c1.y);
    uint32 x0 = E[(size_t)c0.x*64 + lane];
    uint32 x1 = E[(size_t)c1.x*64 + lane];
    ax += v0*bflo(x0) + v1*bflo(x1);
    ay += v0*bfhi(x0) + v1*bfhi(x1);
  }
  if (e < t){
    uint2 c0 = csr[e];
    float v0 = __uint_as_float(c0.y);
    uint32 x0 = E[(size_t)c0.x*64 + lane];
    ax += v0*bflo(x0); ay += v0*bfhi(x0);
  }
  uint32 o = (uint32)f2bf(ax) | ((uint32)f2bf(ay) << 16);
  ((uint32*)tmp_bf)[(size_t)wid*64 + lane] = o;
}

// ---------------- pos tables (fp32): pos_emb @ W.T + b for Q/K/V, u/i ----------------
__global__ void pos_proj(const float* __restrict__ pos_emb,
                         const float* __restrict__ u_in_w, const float* __restrict__ u_in_b,
                         const float* __restrict__ i_in_w, const float* __restrict__ i_in_b,
                         float* __restrict__ pt){
  int j = blockIdx.x;      // 0..16
  int m = blockIdx.y;      // 0..5
  int d = threadIdx.x;     // 0..127
  if (m >= 4 && j > 0) return;
  const float* w; const float* b; float* out; int roff;
  switch (m){
    case 0: w=u_in_w; b=u_in_b; roff=128; out=pt + j*128;            break; // posK_u
    case 1: w=u_in_w; b=u_in_b; roff=256; out=pt + 17*128 + j*128;   break; // posV_u
    case 2: w=i_in_w; b=i_in_b; roff=128; out=pt + 2*17*128 + j*128; break; // posK_i
    case 3: w=i_in_w; b=i_in_b; roff=256; out=pt + 3*17*128 + j*128; break; // posV_i
    case 4: w=u_in_w; b=u_in_b; roff=0;   out=pt + 4*17*128;         break; // posQ_u
    default:w=i_in_w; b=i_in_b; roff=0;   out=pt + 4*17*128 + 128;   break; // posQ_i
  }
  int row = roff + d;
  float acc = b[row];
  for (int c = 0; c < DD; c++) acc += pos_emb[j*DD + c] * w[row*DD + c];
  out[d] = acc;
}

// ---------------- fused projection: K,V over all rows + Q when block in [qlo,qhi) ----------
// 64 rows/block (no boundary straddle: 40000 % 64 == 0 at block granularity... 40000/64=625),
// 4 waves x 16 rows, one A-fragment shared by 3 MFMA chains.
__global__ __launch_bounds__(256,2) void proj3(const ushort_t* __restrict__ A,
    const ushort_t* __restrict__ wq, const ushort_t* __restrict__ wk, const ushort_t* __restrict__ wv,
    ushort_t* __restrict__ Qb, ushort_t* __restrict__ Kb, ushort_t* __restrict__ Vb,
    int qlo, int qhi){
  int tid = threadIdx.x;
  int wvi = tid >> 6, l = tid & 63, lr = l & 15, jg = l >> 4;
  int row0 = blockIdx.x*64 + wvi*16;
  bool doQ = (row0 >= qlo) && (row0 < qhi);
  const bf16x8* Av = (const bf16x8*)A;
  const bf16x8* Bq = (const bf16x8*)wq;
  const bf16x8* Bk = (const bf16x8*)wk;
  const bf16x8* Bv = (const bf16x8*)wv;
  f32x4 accq[8], acck[8], accv[8];
  #pragma unroll
  for (int c=0;c<8;c++){ accq[c]=(f32x4){0,0,0,0}; acck[c]=(f32x4){0,0,0,0}; accv[c]=(f32x4){0,0,0,0}; }

  #pragma unroll
  for (int kc = 0; kc < 4; kc++){
    int ko = kc*4 + jg;
    bf16x8 a = Av[(size_t)(row0 + lr)*16 + ko];
    #pragma unroll
    for (int ct=0;ct<8;ct++){
      size_t bo = (size_t)(ct*16 + lr)*16 + ko;
      acck[ct] = __builtin_amdgcn_mfma_f32_16x16x32_bf16(a, Bk[bo], acck[ct], 0, 0, 0);
      accv[ct] = __builtin_amdgcn_mfma_f32_16x16x32_bf16(a, Bv[bo], accv[ct], 0, 0, 0);
      if (doQ)
        accq[ct] = __builtin_amdgcn_mfma_f32_16x16x32_bf16(a, Bq[bo], accq[ct], 0, 0, 0);
    }
  }
  // C/D layout: col = ct*16 + lr, row = row0 + jg*4 + r
  #pragma unroll
  for (int r=0;r<4;r++){
    int row = row0 + jg*4 + r;
    size_t ro = (size_t)row*128 + lr;
    #pragma unroll
    for (int ct=0;ct<8;ct++){
      Kb[ro + ct*16] = f2bf(acck[ct][r]);
      Vb[ro + ct*16] = f2bf(accv[ct][r]);
      if (doQ) Qb[ro + ct*16] = f2bf(accq[ct][r]);
    }
  }
}

// ---------------- out-projection for both halves + epilogue ----------------
// v = acc + bias + resid(bf16); e_bf = bf16(v); total += v; optional total2 = total.
__global__ __launch_bounds__(256) void out_all(const ushort_t* __restrict__ A,
    const ushort_t* __restrict__ wo_u, const ushort_t* __restrict__ wo_i,
    const float* __restrict__ bu, const float* __restrict__ bi,
    const ushort_t* __restrict__ resid_bf, ushort_t* __restrict__ e_bf,
    float* __restrict__ total, float* __restrict__ total2){
  int tid = threadIdx.x;
  int wvi = tid >> 6, l = tid & 63, lr = l & 15, jg = l >> 4;
  int row0 = blockIdx.x*64 + wvi*16;
  bool isU = row0 < USER_N;
  const bf16x8* Av = (const bf16x8*)A;
  const bf16x8* Bw = (const bf16x8*)(isU ? wo_u : wo_i);
  const float*  bias = isU ? bu : bi;
  f32x4 acc[8];
  #pragma unroll
  for (int c=0;c<8;c++) acc[c]=(f32x4){0,0,0,0};
  #pragma unroll
  for (int kc = 0; kc < 4; kc++){
    int ko = kc*4 + jg;
    bf16x8 a = Av[(size_t)(row0 + lr)*16 + ko];
    #pragma unroll
    for (int ct=0;ct<8;ct++)
      acc[ct] = __builtin_amdgcn_mfma_f32_16x16x32_bf16(a, Bw[(size_t)(ct*16+lr)*16 + ko], acc[ct], 0, 0, 0);
  }
  float bv[8];
  #pragma unroll
  for (int ct=0;ct<8;ct++) bv[ct] = bias[ct*16 + lr];
  #pragma unroll
  for (int r=0;r<4;r++){
    int row = row0 + jg*4 + r;
    size_t ro = (size_t)row*128 + lr;
    #pragma unroll
    for (int ct=0;ct<8;ct++){
      size_t o = ro + ct*16;
      float v = acc[ct][r] + bv[ct] + bf2f(resid_bf[o]);
      e_bf[o] = f2bf(v);
      float tt = total[o] + v;
      total[o] = tt;
      if (total2) total2[o] = tt;
    }
  }
}

// ---------------- attention: one wave per node, L=17, H=4, dh=32; bf16 Q/K/V --------------
__global__ __launch_bounds__(256) void attn_kernel(const ushort_t* __restrict__ QP,
    const ushort_t* __restrict__ KP, const ushort_t* __restrict__ VP,
    const int* __restrict__ samples,
    const float* __restrict__ posQ, const float* __restrict__ posK, const float* __restrict__ posV,
    ushort_t* __restrict__ O, int base, int cnt){
  int wid  = (blockIdx.x*blockDim.x + threadIdx.x) >> 6;
  int lane = threadIdx.x & 63;
  if (wid >= cnt) return;
  int n = base + wid;
  const uint32* Q2 = (const uint32*)QP;
  const uint32* K2 = (const uint32*)KP;
  const uint32* V2 = (const uint32*)VP;
  const float2* pQ2 = (const float2*)posQ;
  const float2* pK2 = (const float2*)posK;
  const float2* pV2 = (const float2*)posV;
  float2 pq = pQ2[lane];
  uint32 qu = Q2[(size_t)n*64 + lane];
  float qx = bflo(qu) + pq.x, qy = bfhi(qu) + pq.y;
  int smp = (lane < KK) ? samples[(size_t)n*KK + lane] : 0;
  float sc[17], vx[17], vy[17];
  #pragma unroll
  for (int j=0;j<17;j++){
    int row = (j==0) ? n : __shfl(smp, j-1, 64);
    uint32 ku = K2[(size_t)row*64 + lane];
    uint32 vu = V2[(size_t)row*64 + lane];
    float2 pk = pK2[j*64 + lane];
    float2 pv = pV2[j*64 + lane];
    float kx = bflo(ku) + pk.x, ky = bfhi(ku) + pk.y;
    vx[j] = bflo(vu) + pv.x; vy[j] = bfhi(vu) + pv.y;
    float p = qx*kx + qy*ky;              // head = lane>>4 (dims 2*lane, 2*lane+1)
    p += __shfl_xor(p, 1, 64);
    p += __shfl_xor(p, 2, 64);
    p += __shfl_xor(p, 4, 64);
    p += __shfl_xor(p, 8, 64);
    sc[j] = p * 0.17677669529663687f;     // 1/sqrt(32)
  }
  float m = sc[0];
  #pragma unroll
  for (int j=1;j<17;j++) m = fmaxf(m, sc[j]);
  float ssum = 0.f;
  #pragma unroll
  for (int j=0;j<17;j++){ sc[j] = __expf(sc[j]-m); ssum += sc[j]; }
  float inv = 1.f/ssum;
  float ox=0.f, oy=0.f;
  #pragma unroll
  for (int j=0;j<17;j++){ ox += sc[j]*vx[j]; oy += sc[j]*vy[j]; }
  uint32 o = (uint32)f2bf(ox*inv) | ((uint32)f2bf(oy*inv) << 16);
  ((uint32*)O)[(size_t)n*64 + lane] = o;
}

extern "C" void kernel_launch(void* const* d_in, const int* in_sizes, int n_in,
                              void* d_out, int out_size, void* d_ws, size_t ws_size,
                              hipStream_t stream){
  const int*   adj_rows = (const int*)d_in[0];
  const int*   adj_cols = (const int*)d_in[1];
  const float* adj_vals = (const float*)d_in[2];
  const int*   samples  = (const int*)d_in[3];
  const float* user_emb = (const float*)d_in[4];
  const float* item_emb = (const float*)d_in[5];
  const float* pos_emb  = (const float*)d_in[6];
  const float* u_in_w   = (const float*)d_in[7];
  const float* u_in_b   = (const float*)d_in[8];
  const float* u_out_w  = (const float*)d_in[9];
  const float* u_out_b  = (const float*)d_in[10];
  const float* i_in_w   = (const float*)d_in[11];
  const float* i_in_b   = (const float*)d_in[12];
  const float* i_out_w  = (const float*)d_in[13];
  const float* i_out_b  = (const float*)d_in[14];
  float* out = (float*)d_out;

  char* ws = (char*)d_ws;
  size_t off = 0;
  auto alloc = [&](size_t bytes)->char*{
    char* p = ws + off; off += (bytes + 255) & ~(size_t)255; return p;
  };
  ushort_t* tmp_bf  = (ushort_t*)alloc((size_t)NN*DD*2);
  ushort_t* e_bf    = (ushort_t*)alloc((size_t)NN*DD*2);
  ushort_t* Qb      = (ushort_t*)alloc((size_t)NN*DD*2);
  ushort_t* Ku      = (ushort_t*)alloc((size_t)NN*DD*2);
  ushort_t* Vu      = (ushort_t*)alloc((size_t)NN*DD*2);
  ushort_t* Ki      = (ushort_t*)alloc((size_t)NN*DD*2);
  ushort_t* Vi      = (ushort_t*)alloc((size_t)NN*DD*2);
  ushort_t* Ob      = (ushort_t*)alloc((size_t)NN*DD*2);
  uint2*    csr     = (uint2*)   alloc((size_t)EE*8);
  int*      counts  = (int*)     alloc((size_t)NN*4);
  int*      row_ptr = (int*)     alloc((size_t)(NN+1)*4);
  int*      cursor  = (int*)     alloc((size_t)NN*4);
  int*      bsum    = (int*)     alloc(320*4);
  int*      bpre    = (int*)     alloc(320*4);
  float*    pt      = (float*)   alloc((size_t)8960*4);
  ushort_t* wbf     = (ushort_t*)alloc((size_t)131072*2);

  float* posK_u = pt;
  float* posV_u = pt + 17*128;
  float* posK_i = pt + 2*17*128;
  float* posV_i = pt + 3*17*128;
  float* posQ_u = pt + 4*17*128;
  float* posQ_i = pt + 4*17*128 + 128;

  ushort_t* wq_u = wbf;
  ushort_t* wk_u = wbf + 16384;
  ushort_t* wv_u = wbf + 2*16384;
  ushort_t* wq_i = wbf + 3*16384;
  ushort_t* wk_i = wbf + 4*16384;
  ushort_t* wv_i = wbf + 5*16384;
  ushort_t* wo_u = wbf + 6*16384;
  ushort_t* wo_i = wbf + 7*16384;

  hipMemsetAsync(counts, 0, (size_t)NN*4, stream);
  init_e_total<<<NN*DD/4/256, 256, 0, stream>>>(user_emb, item_emb, e_bf, out);
  hist_rows<<<(EE+255)/256, 256, 0, stream>>>(adj_rows, counts);
  block_sum<<<313, 256, 0, stream>>>(counts, bsum);
  scan_bsum<<<1, 512, 0, stream>>>(bsum, bpre, row_ptr);
  block_scan<<<313, 256, 0, stream>>>(counts, bpre, row_ptr, cursor);
  scatter_edges<<<(EE+255)/256, 256, 0, stream>>>(adj_rows, adj_cols, adj_vals, cursor, csr);
  pos_proj<<<dim3(17,6), 128, 0, stream>>>(pos_emb, u_in_w, u_in_b, i_in_w, i_in_b, pt);
  cvt_weights<<<512, 256, 0, stream>>>(u_in_w, i_in_w, u_out_w, i_out_w, wbf);

  for (int it = 0; it < 2; it++){
    float* tot2 = (it == 1) ? (out + (size_t)NN*DD) : nullptr;
    spmm_kernel<<<NN/4, 256, 0, stream>>>(row_ptr, csr, e_bf, tmp_bf);
    proj3<<<NN/64, 256, 0, stream>>>(tmp_bf, wq_u, wk_u, wv_u, Qb, Ku, Vu, 0, USER_N);
    proj3<<<NN/64, 256, 0, stream>>>(tmp_bf, wq_i, wk_i, wv_i, Qb, Ki, Vi, USER_N, NN);
    attn_kernel<<<USER_N/4, 256, 0, stream>>>(Qb, Ku, Vu, samples, posQ_u, posK_u, posV_u,
                                              Ob, 0, USER_N);
    attn_kernel<<<ITEM_N/4, 256, 0, stream>>>(Qb, Ki, Vi, samples, posQ_i, posK_i, posV_i,
                                              Ob, USER_N, ITEM_N);
    out_all<<<NN/64, 256, 0, stream>>>(Ob, wo_u, wo_i, u_out_b, i_out_b,
                                       tmp_bf, e_bf, out, tot2);
  }
}

// Round 4
// 1246.476 us; speedup vs baseline: 1.4473x; 1.4473x over previous
//
#include <hip/hip_runtime.h>
#include <hip/hip_bf16.h>
#include <cstdint>
#include <cstddef>

#define USER_N 40000
#define ITEM_N 40000
#define NN     80000
#define DD     128
#define KK     16
#define EE     1600000

typedef __attribute__((ext_vector_type(8))) short bf16x8;
typedef __attribute__((ext_vector_type(4))) float f32x4;
typedef unsigned short ushort_t;
typedef unsigned int   uint32;

static __device__ __forceinline__ ushort_t f2bf(float x){
  __hip_bfloat16 h = __float2bfloat16(x);
  return *reinterpret_cast<ushort_t*>(&h);
}
static __device__ __forceinline__ float bflo(uint32 u){ return __uint_as_float(u << 16); }
static __device__ __forceinline__ float bfhi(uint32 u){ return __uint_as_float(u & 0xffff0000u); }
static __device__ __forceinline__ uint32 pack2(float a, float b){
  return (uint32)f2bf(a) | ((uint32)f2bf(b) << 16);
}

// ---------------- init: e_bf = bf16(concat(user,item)); total(d_out) = concat ----------------
__global__ void init_e_total(const float* __restrict__ user_emb, const float* __restrict__ item_emb,
                             ushort_t* __restrict__ e_bf, float* __restrict__ total){
  int idx = blockIdx.x*blockDim.x + threadIdx.x;           // float4 index
  const int n4 = NN*DD/4;
  if (idx >= n4) return;
  const int u4 = USER_N*DD/4;
  float4 v = (idx < u4) ? ((const float4*)user_emb)[idx] : ((const float4*)item_emb)[idx - u4];
  ((float4*)total)[idx] = v;
  ushort4 b; b.x = f2bf(v.x); b.y = f2bf(v.y); b.z = f2bf(v.z); b.w = f2bf(v.w);
  ((ushort4*)e_bf)[idx] = b;
}

// ---------------- weights -> bf16 ----------------
__global__ void cvt_weights(const float* __restrict__ u_in_w, const float* __restrict__ i_in_w,
                            const float* __restrict__ u_out_w, const float* __restrict__ i_out_w,
                            ushort_t* __restrict__ wbf){
  int i = blockIdx.x*256 + threadIdx.x;   // 512 blocks x 256 = 131072
  float v;
  if      (i < 49152)  v = u_in_w[i];
  else if (i < 98304)  v = i_in_w[i - 49152];
  else if (i < 114688) v = u_out_w[i - 98304];
  else                 v = i_out_w[i - 114688];
  wbf[i] = f2bf(v);
}

// ---------------- CSR build ----------------
__global__ void hist_rows(const int* __restrict__ rows, int* __restrict__ counts){
  int i = blockIdx.x*blockDim.x + threadIdx.x;
  if (i < EE) atomicAdd(&counts[rows[i]], 1);
}

__global__ void block_sum(const int* __restrict__ counts, int* __restrict__ bsum){
  __shared__ int s[256];
  int i = blockIdx.x*256 + threadIdx.x;
  s[threadIdx.x] = (i < NN) ? counts[i] : 0;
  __syncthreads();
  for (int o = 128; o > 0; o >>= 1){
    if (threadIdx.x < o) s[threadIdx.x] += s[threadIdx.x + o];
    __syncthreads();
  }
  if (threadIdx.x == 0) bsum[blockIdx.x] = s[0];
}

__global__ void scan_bsum(const int* __restrict__ bsum, int* __restrict__ bpre,
                          int* __restrict__ row_ptr){
  __shared__ int s[512];
  int v = (threadIdx.x < 313) ? bsum[threadIdx.x] : 0;
  s[threadIdx.x] = v;
  __syncthreads();
  for (int o = 1; o < 512; o <<= 1){
    int t = (threadIdx.x >= o) ? s[threadIdx.x - o] : 0;
    __syncthreads();
    s[threadIdx.x] += t;
    __syncthreads();
  }
  if (threadIdx.x < 313) bpre[threadIdx.x] = s[threadIdx.x] - v;
  if (threadIdx.x == 312) row_ptr[NN] = s[312];
}

__global__ void block_scan(const int* __restrict__ counts, const int* __restrict__ bpre,
                           int* __restrict__ row_ptr, int* __restrict__ cursor){
  __shared__ int s[256];
  int i = blockIdx.x*256 + threadIdx.x;
  int v = (i < NN) ? counts[i] : 0;
  s[threadIdx.x] = v;
  __syncthreads();
  for (int o = 1; o < 256; o <<= 1){
    int t = (threadIdx.x >= o) ? s[threadIdx.x - o] : 0;
    __syncthreads();
    s[threadIdx.x] += t;
    __syncthreads();
  }
  if (i < NN){
    int ex = bpre[blockIdx.x] + s[threadIdx.x] - v;
    row_ptr[i] = ex; cursor[i] = ex;
  }
}

// packed (col, val) single 8B store per edge
__global__ void scatter_edges(const int* __restrict__ rows, const int* __restrict__ cols,
                              const float* __restrict__ vals, int* __restrict__ cursor,
                              uint2* __restrict__ csr){
  int i = blockIdx.x*blockDim.x + threadIdx.x;
  if (i >= EE) return;
  int r = rows[i];
  int p = atomicAdd(&cursor[r], 1);
  csr[p] = make_uint2((uint32)cols[i], __float_as_uint(vals[i]));
}

// ---------------- SpMM: one wave per row; bf16 gather (256B/row), bf16 output ----------
__global__ __launch_bounds__(256) void spmm_kernel(const int* __restrict__ row_ptr,
    const uint2* __restrict__ csr, const ushort_t* __restrict__ e_bf,
    ushort_t* __restrict__ tmp_bf){
  int wid  = (blockIdx.x*blockDim.x + threadIdx.x) >> 6;
  int lane = threadIdx.x & 63;
  if (wid >= NN) return;
  int s = row_ptr[wid], t = row_ptr[wid+1];
  const uint32* E = (const uint32*)e_bf;   // 2 bf16 per uint
  float ax = 0.f, ay = 0.f;
  int e = s;
  for (; e + 1 < t; e += 2){
    uint2 c0 = csr[e], c1 = csr[e+1];
    float v0 = __uint_as_float(c0.y), v1 = __uint_as_float(c1.y);
    uint32 x0 = E[(size_t)c0.x*64 + lane];
    uint32 x1 = E[(size_t)c1.x*64 + lane];
    ax += v0*bflo(x0) + v1*bflo(x1);
    ay += v0*bfhi(x0) + v1*bfhi(x1);
  }
  if (e < t){
    uint2 c0 = csr[e];
    float v0 = __uint_as_float(c0.y);
    uint32 x0 = E[(size_t)c0.x*64 + lane];
    ax += v0*bflo(x0); ay += v0*bfhi(x0);
  }
  ((uint32*)tmp_bf)[(size_t)wid*64 + lane] = pack2(ax, ay);
}

// ---------------- pos tables (fp32): pos_emb @ W.T + b for Q/K/V, u/i ----------------
__global__ void pos_proj(const float* __restrict__ pos_emb,
                         const float* __restrict__ u_in_w, const float* __restrict__ u_in_b,
                         const float* __restrict__ i_in_w, const float* __restrict__ i_in_b,
                         float* __restrict__ pt){
  int j = blockIdx.x;      // 0..16
  int m = blockIdx.y;      // 0..5
  int d = threadIdx.x;     // 0..127
  if (m >= 4 && j > 0) return;
  const float* w; const float* b; float* out; int roff;
  switch (m){
    case 0: w=u_in_w; b=u_in_b; roff=128; out=pt + j*128;            break; // posK_u
    case 1: w=u_in_w; b=u_in_b; roff=256; out=pt + 17*128 + j*128;   break; // posV_u
    case 2: w=i_in_w; b=i_in_b; roff=128; out=pt + 2*17*128 + j*128; break; // posK_i
    case 3: w=i_in_w; b=i_in_b; roff=256; out=pt + 3*17*128 + j*128; break; // posV_i
    case 4: w=u_in_w; b=u_in_b; roff=0;   out=pt + 4*17*128;         break; // posQ_u
    default:w=i_in_w; b=i_in_b; roff=0;   out=pt + 4*17*128 + 128;   break; // posQ_i
  }
  int row = roff + d;
  float acc = b[row];
  for (int c = 0; c < DD; c++) acc += pos_emb[j*DD + c] * w[row*DD + c];
  out[d] = acc;
}

// ---- wave-private LDS transpose of a 16x128 MFMA C-tile, then coalesced bf16 stores ----
// T: per-wave fp32 buffer, row stride 132 (2-way write conflicts only; rows 16B-aligned).
static __device__ __forceinline__ void tile_store_bf16(float* __restrict__ T,
    const f32x4* acc, ushort_t* __restrict__ dst, int row0, int jg, int lr, int l){
  #pragma unroll
  for (int r=0;r<4;r++){
    int row = jg*4 + r;
    #pragma unroll
    for (int ct=0;ct<8;ct++) T[row*132 + ct*16 + lr] = acc[ct][r];
  }
  // wave-private: no barrier needed, compiler orders ds via lgkmcnt
  #pragma unroll
  for (int i=0;i<4;i++){
    int row = l & 15;
    int p = (l >> 4) + 4*i;          // 16B-pair index 0..15 (8 cols each)
    const float* src = &T[row*132 + p*8];
    float4 a = *(const float4*)src;
    float4 b = *(const float4*)(src + 4);
    uint4 w = make_uint4(pack2(a.x,a.y), pack2(a.z,a.w), pack2(b.x,b.y), pack2(b.z,b.w));
    *(uint4*)&dst[(size_t)(row0 + row)*128 + p*8] = w;
  }
}

// ---------------- fused projection: K,V over all rows + Q when wave in [qlo,qhi) ----------
// 64 rows/block, 4 waves x 16 rows, one A-fragment shared by 3 MFMA chains.
__global__ __launch_bounds__(256) void proj3(const ushort_t* __restrict__ A,
    const ushort_t* __restrict__ wq, const ushort_t* __restrict__ wk, const ushort_t* __restrict__ wv,
    ushort_t* __restrict__ Qb, ushort_t* __restrict__ Kb, ushort_t* __restrict__ Vb,
    int qlo, int qhi){
  __shared__ float lds[4][16*132];
  int tid = threadIdx.x;
  int wvi = tid >> 6, l = tid & 63, lr = l & 15, jg = l >> 4;
  int row0 = blockIdx.x*64 + wvi*16;
  bool doQ = (row0 >= qlo) && (row0 < qhi);
  const bf16x8* Av = (const bf16x8*)A;
  const bf16x8* Bq = (const bf16x8*)wq;
  const bf16x8* Bk = (const bf16x8*)wk;
  const bf16x8* Bv = (const bf16x8*)wv;
  f32x4 accq[8], acck[8], accv[8];
  #pragma unroll
  for (int c=0;c<8;c++){ accq[c]=(f32x4){0,0,0,0}; acck[c]=(f32x4){0,0,0,0}; accv[c]=(f32x4){0,0,0,0}; }

  #pragma unroll
  for (int kc = 0; kc < 4; kc++){
    int ko = kc*4 + jg;
    bf16x8 a = Av[(size_t)(row0 + lr)*16 + ko];
    #pragma unroll
    for (int ct=0;ct<8;ct++){
      size_t bo = (size_t)(ct*16 + lr)*16 + ko;
      acck[ct] = __builtin_amdgcn_mfma_f32_16x16x32_bf16(a, Bk[bo], acck[ct], 0, 0, 0);
      accv[ct] = __builtin_amdgcn_mfma_f32_16x16x32_bf16(a, Bv[bo], accv[ct], 0, 0, 0);
      if (doQ)
        accq[ct] = __builtin_amdgcn_mfma_f32_16x16x32_bf16(a, Bq[bo], accq[ct], 0, 0, 0);
    }
  }
  float* T = lds[wvi];
  tile_store_bf16(T, acck, Kb, row0, jg, lr, l);
  tile_store_bf16(T, accv, Vb, row0, jg, lr, l);
  if (doQ) tile_store_bf16(T, accq, Qb, row0, jg, lr, l);
}

// ---------------- out-projection for both halves + fully-coalesced epilogue ----------------
// v = acc + bias + resid(bf16); e_bf = bf16(v); total += v; optional total2 = total.
__global__ __launch_bounds__(256) void out_all(const ushort_t* __restrict__ A,
    const ushort_t* __restrict__ wo_u, const ushort_t* __restrict__ wo_i,
    const float* __restrict__ bu, const float* __restrict__ bi_,
    const ushort_t* __restrict__ resid_bf, ushort_t* __restrict__ e_bf,
    float* __restrict__ total, float* __restrict__ total2){
  __shared__ float lds[4][16*132];
  int tid = threadIdx.x;
  int wvi = tid >> 6, l = tid & 63, lr = l & 15, jg = l >> 4;
  int row0 = blockIdx.x*64 + wvi*16;
  bool isU = row0 < USER_N;
  const bf16x8* Av = (const bf16x8*)A;
  const bf16x8* Bw = (const bf16x8*)(isU ? wo_u : wo_i);
  const float*  bias = isU ? bu : bi_;
  f32x4 acc[8];
  #pragma unroll
  for (int c=0;c<8;c++) acc[c]=(f32x4){0,0,0,0};
  #pragma unroll
  for (int kc = 0; kc < 4; kc++){
    int ko = kc*4 + jg;
    bf16x8 a = Av[(size_t)(row0 + lr)*16 + ko];
    #pragma unroll
    for (int ct=0;ct<8;ct++)
      acc[ct] = __builtin_amdgcn_mfma_f32_16x16x32_bf16(a, Bw[(size_t)(ct*16+lr)*16 + ko], acc[ct], 0, 0, 0);
  }
  float* T = lds[wvi];
  #pragma unroll
  for (int r=0;r<4;r++){
    int row = jg*4 + r;
    #pragma unroll
    for (int ct=0;ct<8;ct++) T[row*132 + ct*16 + lr] = acc[ct][r];
  }
  #pragma unroll
  for (int i=0;i<4;i++){
    int row = l & 15;
    int p = (l >> 4) + 4*i;
    int grow = row0 + row;
    size_t o = (size_t)grow*128 + p*8;
    const float* src = &T[row*132 + p*8];
    float4 a = *(const float4*)src;
    float4 b = *(const float4*)(src + 4);
    float4 ba = *(const float4*)&bias[p*8];
    float4 bb = *(const float4*)&bias[p*8 + 4];
    uint4 rr = *(const uint4*)&resid_bf[o];
    a.x += ba.x + bflo(rr.x); a.y += ba.y + bfhi(rr.x);
    a.z += ba.z + bflo(rr.y); a.w += ba.w + bfhi(rr.y);
    b.x += bb.x + bflo(rr.z); b.y += bb.y + bfhi(rr.z);
    b.z += bb.z + bflo(rr.w); b.w += bb.w + bfhi(rr.w);
    *(uint4*)&e_bf[o] = make_uint4(pack2(a.x,a.y), pack2(a.z,a.w), pack2(b.x,b.y), pack2(b.z,b.w));
    float4 t0 = *(const float4*)&total[o];
    float4 t1 = *(const float4*)&total[o + 4];
    t0.x += a.x; t0.y += a.y; t0.z += a.z; t0.w += a.w;
    t1.x += b.x; t1.y += b.y; t1.z += b.z; t1.w += b.w;
    *(float4*)&total[o]     = t0;
    *(float4*)&total[o + 4] = t1;
    if (total2){
      *(float4*)&total2[o]     = t0;
      *(float4*)&total2[o + 4] = t1;
    }
  }
}

// ---------------- attention: one wave per node, L=17, H=4, dh=32; bf16 Q/K/V --------------
__global__ __launch_bounds__(256) void attn_kernel(const ushort_t* __restrict__ QP,
    const ushort_t* __restrict__ KP, const ushort_t* __restrict__ VP,
    const int* __restrict__ samples,
    const float* __restrict__ posQ, const float* __restrict__ posK, const float* __restrict__ posV,
    ushort_t* __restrict__ O, int base, int cnt){
  int wid  = (blockIdx.x*blockDim.x + threadIdx.x) >> 6;
  int lane = threadIdx.x & 63;
  if (wid >= cnt) return;
  int n = base + wid;
  const uint32* Q2 = (const uint32*)QP;
  const uint32* K2 = (const uint32*)KP;
  const uint32* V2 = (const uint32*)VP;
  const float2* pQ2 = (const float2*)posQ;
  const float2* pK2 = (const float2*)posK;
  const float2* pV2 = (const float2*)posV;
  float2 pq = pQ2[lane];
  uint32 qu = Q2[(size_t)n*64 + lane];
  float qx = bflo(qu) + pq.x, qy = bfhi(qu) + pq.y;
  int smp = (lane < KK) ? samples[(size_t)n*KK + lane] : 0;
  float sc[17], vx[17], vy[17];
  #pragma unroll
  for (int j=0;j<17;j++){
    int row = (j==0) ? n : __shfl(smp, j-1, 64);
    uint32 ku = K2[(size_t)row*64 + lane];
    uint32 vu = V2[(size_t)row*64 + lane];
    float2 pk = pK2[j*64 + lane];
    float2 pv = pV2[j*64 + lane];
    float kx = bflo(ku) + pk.x, ky = bfhi(ku) + pk.y;
    vx[j] = bflo(vu) + pv.x; vy[j] = bfhi(vu) + pv.y;
    float p = qx*kx + qy*ky;              // head = lane>>4 (dims 2*lane, 2*lane+1)
    p += __shfl_xor(p, 1, 64);
    p += __shfl_xor(p, 2, 64);
    p += __shfl_xor(p, 4, 64);
    p += __shfl_xor(p, 8, 64);
    sc[j] = p * 0.17677669529663687f;     // 1/sqrt(32)
  }
  float m = sc[0];
  #pragma unroll
  for (int j=1;j<17;j++) m = fmaxf(m, sc[j]);
  float ssum = 0.f;
  #pragma unroll
  for (int j=0;j<17;j++){ sc[j] = __expf(sc[j]-m); ssum += sc[j]; }
  float inv = 1.f/ssum;
  float ox=0.f, oy=0.f;
  #pragma unroll
  for (int j=0;j<17;j++){ ox += sc[j]*vx[j]; oy += sc[j]*vy[j]; }
  ((uint32*)O)[(size_t)n*64 + lane] = pack2(ox*inv, oy*inv);
}

extern "C" void kernel_launch(void* const* d_in, const int* in_sizes, int n_in,
                              void* d_out, int out_size, void* d_ws, size_t ws_size,
                              hipStream_t stream){
  const int*   adj_rows = (const int*)d_in[0];
  const int*   adj_cols = (const int*)d_in[1];
  const float* adj_vals = (const float*)d_in[2];
  const int*   samples  = (const int*)d_in[3];
  const float* user_emb = (const float*)d_in[4];
  const float* item_emb = (const float*)d_in[5];
  const float* pos_emb  = (const float*)d_in[6];
  const float* u_in_w   = (const float*)d_in[7];
  const float* u_in_b   = (const float*)d_in[8];
  const float* u_out_w  = (const float*)d_in[9];
  const float* u_out_b  = (const float*)d_in[10];
  const float* i_in_w   = (const float*)d_in[11];
  const float* i_in_b   = (const float*)d_in[12];
  const float* i_out_w  = (const float*)d_in[13];
  const float* i_out_b  = (const float*)d_in[14];
  float* out = (float*)d_out;

  char* ws = (char*)d_ws;
  size_t off = 0;
  auto alloc = [&](size_t bytes)->char*{
    char* p = ws + off; off += (bytes + 255) & ~(size_t)255; return p;
  };
  ushort_t* tmp_bf  = (ushort_t*)alloc((size_t)NN*DD*2);
  ushort_t* e_bf    = (ushort_t*)alloc((size_t)NN*DD*2);
  ushort_t* Qb      = (ushort_t*)alloc((size_t)NN*DD*2);
  ushort_t* Ku      = (ushort_t*)alloc((size_t)NN*DD*2);
  ushort_t* Vu      = (ushort_t*)alloc((size_t)NN*DD*2);
  ushort_t* Ki      = (ushort_t*)alloc((size_t)NN*DD*2);
  ushort_t* Vi      = (ushort_t*)alloc((size_t)NN*DD*2);
  ushort_t* Ob      = (ushort_t*)alloc((size_t)NN*DD*2);
  uint2*    csr     = (uint2*)   alloc((size_t)EE*8);
  int*      counts  = (int*)     alloc((size_t)NN*4);
  int*      row_ptr = (int*)     alloc((size_t)(NN+1)*4);
  int*      cursor  = (int*)     alloc((size_t)NN*4);
  int*      bsum    = (int*)     alloc(320*4);
  int*      bpre    = (int*)     alloc(320*4);
  float*    pt      = (float*)   alloc((size_t)8960*4);
  ushort_t* wbf     = (ushort_t*)alloc((size_t)131072*2);

  float* posK_u = pt;
  float* posV_u = pt + 17*128;
  float* posK_i = pt + 2*17*128;
  float* posV_i = pt + 3*17*128;
  float* posQ_u = pt + 4*17*128;
  float* posQ_i = pt + 4*17*128 + 128;

  ushort_t* wq_u = wbf;
  ushort_t* wk_u = wbf + 16384;
  ushort_t* wv_u = wbf + 2*16384;
  ushort_t* wq_i = wbf + 3*16384;
  ushort_t* wk_i = wbf + 4*16384;
  ushort_t* wv_i = wbf + 5*16384;
  ushort_t* wo_u = wbf + 6*16384;
  ushort_t* wo_i = wbf + 7*16384;

  hipMemsetAsync(counts, 0, (size_t)NN*4, stream);
  init_e_total<<<NN*DD/4/256, 256, 0, stream>>>(user_emb, item_emb, e_bf, out);
  hist_rows<<<(EE+255)/256, 256, 0, stream>>>(adj_rows, counts);
  block_sum<<<313, 256, 0, stream>>>(counts, bsum);
  scan_bsum<<<1, 512, 0, stream>>>(bsum, bpre, row_ptr);
  block_scan<<<313, 256, 0, stream>>>(counts, bpre, row_ptr, cursor);
  scatter_edges<<<(EE+255)/256, 256, 0, stream>>>(adj_rows, adj_cols, adj_vals, cursor, csr);
  pos_proj<<<dim3(17,6), 128, 0, stream>>>(pos_emb, u_in_w, u_in_b, i_in_w, i_in_b, pt);
  cvt_weights<<<512, 256, 0, stream>>>(u_in_w, i_in_w, u_out_w, i_out_w, wbf);

  for (int it = 0; it < 2; it++){
    float* tot2 = (it == 1) ? (out + (size_t)NN*DD) : nullptr;
    spmm_kernel<<<NN/4, 256, 0, stream>>>(row_ptr, csr, e_bf, tmp_bf);
    proj3<<<NN/64, 256, 0, stream>>>(tmp_bf, wq_u, wk_u, wv_u, Qb, Ku, Vu, 0, USER_N);
    proj3<<<NN/64, 256, 0, stream>>>(tmp_bf, wq_i, wk_i, wv_i, Qb, Ki, Vi, USER_N, NN);
    attn_kernel<<<USER_N/4, 256, 0, stream>>>(Qb, Ku, Vu, samples, posQ_u, posK_u, posV_u,
                                              Ob, 0, USER_N);
    attn_kernel<<<ITEM_N/4, 256, 0, stream>>>(Qb, Ki, Vi, samples, posQ_i, posK_i, posV_i,
                                              Ob, USER_N, ITEM_N);
    out_all<<<NN/64, 256, 0, stream>>>(Ob, wo_u, wo_i, u_out_b, i_out_b,
                                       tmp_bf, e_bf, out, tot2);
  }
}

// Round 5
// 1150.519 us; speedup vs baseline: 1.5680x; 1.0834x over previous
//
#include <hip/hip_runtime.h>
#include <hip/hip_bf16.h>
#include <cstdint>
#include <cstddef>

#define USER_N 40000
#define ITEM_N 40000
#define NN     80000
#define DD     128
#define KK     16
#define EE     1600000

typedef __attribute__((ext_vector_type(8))) short bf16x8;
typedef __attribute__((ext_vector_type(4))) float f32x4;
typedef unsigned short ushort_t;
typedef unsigned int   uint32;

static __device__ __forceinline__ ushort_t f2bf(float x){
  __hip_bfloat16 h = __float2bfloat16(x);
  return *reinterpret_cast<ushort_t*>(&h);
}
static __device__ __forceinline__ float bflo(uint32 u){ return __uint_as_float(u << 16); }
static __device__ __forceinline__ float bfhi(uint32 u){ return __uint_as_float(u & 0xffff0000u); }
static __device__ __forceinline__ uint32 pack2(float a, float b){
  return (uint32)f2bf(a) | ((uint32)f2bf(b) << 16);
}

// ---------------- init: e_bf = bf16(concat(user,item)); total(d_out) = concat ----------------
__global__ void init_e_total(const float* __restrict__ user_emb, const float* __restrict__ item_emb,
                             ushort_t* __restrict__ e_bf, float* __restrict__ total){
  int idx = blockIdx.x*blockDim.x + threadIdx.x;           // float4 index
  const int n4 = NN*DD/4;
  if (idx >= n4) return;
  const int u4 = USER_N*DD/4;
  float4 v = (idx < u4) ? ((const float4*)user_emb)[idx] : ((const float4*)item_emb)[idx - u4];
  ((float4*)total)[idx] = v;
  ushort4 b; b.x = f2bf(v.x); b.y = f2bf(v.y); b.z = f2bf(v.z); b.w = f2bf(v.w);
  ((ushort4*)e_bf)[idx] = b;
}

// ---------------- weights -> bf16 ----------------
__global__ void cvt_weights(const float* __restrict__ u_in_w, const float* __restrict__ i_in_w,
                            const float* __restrict__ u_out_w, const float* __restrict__ i_out_w,
                            ushort_t* __restrict__ wbf){
  int i = blockIdx.x*256 + threadIdx.x;   // 512 blocks x 256 = 131072
  float v;
  if      (i < 49152)  v = u_in_w[i];
  else if (i < 98304)  v = i_in_w[i - 49152];
  else if (i < 114688) v = u_out_w[i - 98304];
  else                 v = i_out_w[i - 114688];
  wbf[i] = f2bf(v);
}

// ---------------- CSR build ----------------
__global__ void hist_rows(const int* __restrict__ rows, int* __restrict__ counts){
  int i = blockIdx.x*blockDim.x + threadIdx.x;
  if (i < EE) atomicAdd(&counts[rows[i]], 1);
}

__global__ void block_sum(const int* __restrict__ counts, int* __restrict__ bsum){
  __shared__ int s[256];
  int i = blockIdx.x*256 + threadIdx.x;
  s[threadIdx.x] = (i < NN) ? counts[i] : 0;
  __syncthreads();
  for (int o = 128; o > 0; o >>= 1){
    if (threadIdx.x < o) s[threadIdx.x] += s[threadIdx.x + o];
    __syncthreads();
  }
  if (threadIdx.x == 0) bsum[blockIdx.x] = s[0];
}

__global__ void scan_bsum(const int* __restrict__ bsum, int* __restrict__ bpre,
                          int* __restrict__ row_ptr){
  __shared__ int s[512];
  int v = (threadIdx.x < 313) ? bsum[threadIdx.x] : 0;
  s[threadIdx.x] = v;
  __syncthreads();
  for (int o = 1; o < 512; o <<= 1){
    int t = (threadIdx.x >= o) ? s[threadIdx.x - o] : 0;
    __syncthreads();
    s[threadIdx.x] += t;
    __syncthreads();
  }
  if (threadIdx.x < 313) bpre[threadIdx.x] = s[threadIdx.x] - v;
  if (threadIdx.x == 312) row_ptr[NN] = s[312];
}

__global__ void block_scan(const int* __restrict__ counts, const int* __restrict__ bpre,
                           int* __restrict__ row_ptr, int* __restrict__ cursor){
  __shared__ int s[256];
  int i = blockIdx.x*256 + threadIdx.x;
  int v = (i < NN) ? counts[i] : 0;
  s[threadIdx.x] = v;
  __syncthreads();
  for (int o = 1; o < 256; o <<= 1){
    int t = (threadIdx.x >= o) ? s[threadIdx.x - o] : 0;
    __syncthreads();
    s[threadIdx.x] += t;
    __syncthreads();
  }
  if (i < NN){
    int ex = bpre[blockIdx.x] + s[threadIdx.x] - v;
    row_ptr[i] = ex; cursor[i] = ex;
  }
}

// packed (col, val) single 8B store per edge
__global__ void scatter_edges(const int* __restrict__ rows, const int* __restrict__ cols,
                              const float* __restrict__ vals, int* __restrict__ cursor,
                              uint2* __restrict__ csr){
  int i = blockIdx.x*blockDim.x + threadIdx.x;
  if (i >= EE) return;
  int r = rows[i];
  int p = atomicAdd(&cursor[r], 1);
  csr[p] = make_uint2((uint32)cols[i], __float_as_uint(vals[i]));
}

// ---------------- SpMM: one wave per row; bf16 gather (256B/row), bf16 output ----------
__global__ __launch_bounds__(256) void spmm_kernel(const int* __restrict__ row_ptr,
    const uint2* __restrict__ csr, const ushort_t* __restrict__ e_bf,
    ushort_t* __restrict__ tmp_bf){
  int wid  = (blockIdx.x*blockDim.x + threadIdx.x) >> 6;
  int lane = threadIdx.x & 63;
  if (wid >= NN) return;
  int s = row_ptr[wid], t = row_ptr[wid+1];
  const uint32* E = (const uint32*)e_bf;   // 2 bf16 per uint
  float ax = 0.f, ay = 0.f;
  int e = s;
  for (; e + 1 < t; e += 2){
    uint2 c0 = csr[e], c1 = csr[e+1];
    float v0 = __uint_as_float(c0.y), v1 = __uint_as_float(c1.y);
    uint32 x0 = E[(size_t)c0.x*64 + lane];
    uint32 x1 = E[(size_t)c1.x*64 + lane];
    ax += v0*bflo(x0) + v1*bflo(x1);
    ay += v0*bfhi(x0) + v1*bfhi(x1);
  }
  if (e < t){
    uint2 c0 = csr[e];
    float v0 = __uint_as_float(c0.y);
    uint32 x0 = E[(size_t)c0.x*64 + lane];
    ax += v0*bflo(x0); ay += v0*bfhi(x0);
  }
  ((uint32*)tmp_bf)[(size_t)wid*64 + lane] = pack2(ax, ay);
}

// ---------------- pos tables (fp32): pos_emb @ W.T + b for Q/K/V, u/i ----------------
__global__ void pos_proj(const float* __restrict__ pos_emb,
                         const float* __restrict__ u_in_w, const float* __restrict__ u_in_b,
                         const float* __restrict__ i_in_w, const float* __restrict__ i_in_b,
                         float* __restrict__ pt){
  int j = blockIdx.x;      // 0..16
  int m = blockIdx.y;      // 0..5
  int d = threadIdx.x;     // 0..127
  if (m >= 4 && j > 0) return;
  const float* w; const float* b; float* out; int roff;
  switch (m){
    case 0: w=u_in_w; b=u_in_b; roff=128; out=pt + j*128;            break; // posK_u
    case 1: w=u_in_w; b=u_in_b; roff=256; out=pt + 17*128 + j*128;   break; // posV_u
    case 2: w=i_in_w; b=i_in_b; roff=128; out=pt + 2*17*128 + j*128; break; // posK_i
    case 3: w=i_in_w; b=i_in_b; roff=256; out=pt + 3*17*128 + j*128; break; // posV_i
    case 4: w=u_in_w; b=u_in_b; roff=0;   out=pt + 4*17*128;         break; // posQ_u
    default:w=i_in_w; b=i_in_b; roff=0;   out=pt + 4*17*128 + 128;   break; // posQ_i
  }
  int row = roff + d;
  float acc = b[row];
  for (int c = 0; c < DD; c++) acc += pos_emb[j*DD + c] * w[row*DD + c];
  out[d] = acc;
}

// ---- wave-private LDS transpose of a 16x128 MFMA C-tile, then coalesced bf16 stores ----
static __device__ __forceinline__ void tile_store_bf16(float* __restrict__ T,
    const f32x4* acc, ushort_t* __restrict__ dst, int row0, int jg, int lr, int l){
  #pragma unroll
  for (int r=0;r<4;r++){
    int row = jg*4 + r;
    #pragma unroll
    for (int ct=0;ct<8;ct++) T[row*132 + ct*16 + lr] = acc[ct][r];
  }
  // wave-private: no barrier needed, compiler orders ds via lgkmcnt
  #pragma unroll
  for (int i=0;i<4;i++){
    int row = l & 15;
    int p = (l >> 4) + 4*i;          // 16B-pair index 0..15 (8 cols each)
    const float* src = &T[row*132 + p*8];
    float4 a = *(const float4*)src;
    float4 b = *(const float4*)(src + 4);
    uint4 w = make_uint4(pack2(a.x,a.y), pack2(a.z,a.w), pack2(b.x,b.y), pack2(b.z,b.w));
    *(uint4*)&dst[(size_t)(row0 + row)*128 + p*8] = w;
  }
}

// ---------------- single-matrix GEMM: one wave = 16 rows x 128 cols, K=128 ----------------
// W0 used for rows < USER_N, W1 otherwise (pass same pointer for fixed-weight launches).
// acc = 32 VGPR; B working set = one 32KB matrix (L1-resident); 4 waves/SIMD.
__global__ __launch_bounds__(256,4) void gemm16(const ushort_t* __restrict__ A,
    const ushort_t* __restrict__ W0, const ushort_t* __restrict__ W1,
    ushort_t* __restrict__ dst){
  __shared__ float lds[4][16*132];
  int tid = threadIdx.x;
  int wvi = tid >> 6, l = tid & 63, lr = l & 15, jg = l >> 4;
  int row0 = blockIdx.x*64 + wvi*16;
  const bf16x8* Av = (const bf16x8*)A;
  const bf16x8* Bw = (const bf16x8*)((row0 < USER_N) ? W0 : W1);
  f32x4 acc[8];
  #pragma unroll
  for (int c=0;c<8;c++) acc[c]=(f32x4){0,0,0,0};
  #pragma unroll
  for (int kc = 0; kc < 4; kc++){
    int ko = kc*4 + jg;
    bf16x8 a = Av[(size_t)(row0 + lr)*16 + ko];
    #pragma unroll
    for (int ct=0;ct<8;ct++)
      acc[ct] = __builtin_amdgcn_mfma_f32_16x16x32_bf16(a, Bw[(size_t)(ct*16+lr)*16 + ko], acc[ct], 0, 0, 0);
  }
  tile_store_bf16(lds[wvi], acc, dst, row0, jg, lr, l);
}

// ---------------- out-projection (wave-uniform weight select) + coalesced epilogue -------
// v = acc + bias + resid(bf16); e_bf = bf16(v); total += v; optional total2 = total.
__global__ __launch_bounds__(256,4) void out_all(const ushort_t* __restrict__ A,
    const ushort_t* __restrict__ wo_u, const ushort_t* __restrict__ wo_i,
    const float* __restrict__ bu, const float* __restrict__ bi_,
    const ushort_t* __restrict__ resid_bf, ushort_t* __restrict__ e_bf,
    float* __restrict__ total, float* __restrict__ total2){
  __shared__ float lds[4][16*132];
  int tid = threadIdx.x;
  int wvi = tid >> 6, l = tid & 63, lr = l & 15, jg = l >> 4;
  int row0 = blockIdx.x*64 + wvi*16;
  bool isU = row0 < USER_N;
  const bf16x8* Av = (const bf16x8*)A;
  const bf16x8* Bw = (const bf16x8*)(isU ? wo_u : wo_i);
  const float*  bias = isU ? bu : bi_;
  f32x4 acc[8];
  #pragma unroll
  for (int c=0;c<8;c++) acc[c]=(f32x4){0,0,0,0};
  #pragma unroll
  for (int kc = 0; kc < 4; kc++){
    int ko = kc*4 + jg;
    bf16x8 a = Av[(size_t)(row0 + lr)*16 + ko];
    #pragma unroll
    for (int ct=0;ct<8;ct++)
      acc[ct] = __builtin_amdgcn_mfma_f32_16x16x32_bf16(a, Bw[(size_t)(ct*16+lr)*16 + ko], acc[ct], 0, 0, 0);
  }
  float* T = lds[wvi];
  #pragma unroll
  for (int r=0;r<4;r++){
    int row = jg*4 + r;
    #pragma unroll
    for (int ct=0;ct<8;ct++) T[row*132 + ct*16 + lr] = acc[ct][r];
  }
  #pragma unroll
  for (int i=0;i<4;i++){
    int row = l & 15;
    int p = (l >> 4) + 4*i;
    int grow = row0 + row;
    size_t o = (size_t)grow*128 + p*8;
    const float* src = &T[row*132 + p*8];
    float4 a = *(const float4*)src;
    float4 b = *(const float4*)(src + 4);
    float4 ba = *(const float4*)&bias[p*8];
    float4 bb = *(const float4*)&bias[p*8 + 4];
    uint4 rr = *(const uint4*)&resid_bf[o];
    a.x += ba.x + bflo(rr.x); a.y += ba.y + bfhi(rr.x);
    a.z += ba.z + bflo(rr.y); a.w += ba.w + bfhi(rr.y);
    b.x += bb.x + bflo(rr.z); b.y += bb.y + bfhi(rr.z);
    b.z += bb.z + bflo(rr.w); b.w += bb.w + bfhi(rr.w);
    *(uint4*)&e_bf[o] = make_uint4(pack2(a.x,a.y), pack2(a.z,a.w), pack2(b.x,b.y), pack2(b.z,b.w));
    float4 t0 = *(const float4*)&total[o];
    float4 t1 = *(const float4*)&total[o + 4];
    t0.x += a.x; t0.y += a.y; t0.z += a.z; t0.w += a.w;
    t1.x += b.x; t1.y += b.y; t1.z += b.z; t1.w += b.w;
    *(float4*)&total[o]     = t0;
    *(float4*)&total[o + 4] = t1;
    if (total2){
      *(float4*)&total2[o]     = t0;
      *(float4*)&total2[o + 4] = t1;
    }
  }
}

// ---------------- attention: one wave per node, L=17, H=4, dh=32; bf16 Q/K/V --------------
__global__ __launch_bounds__(256) void attn_kernel(const ushort_t* __restrict__ QP,
    const ushort_t* __restrict__ KP, const ushort_t* __restrict__ VP,
    const int* __restrict__ samples,
    const float* __restrict__ posQ, const float* __restrict__ posK, const float* __restrict__ posV,
    ushort_t* __restrict__ O, int base, int cnt){
  int wid  = (blockIdx.x*blockDim.x + threadIdx.x) >> 6;
  int lane = threadIdx.x & 63;
  if (wid >= cnt) return;
  int n = base + wid;
  const uint32* Q2 = (const uint32*)QP;
  const uint32* K2 = (const uint32*)KP;
  const uint32* V2 = (const uint32*)VP;
  const float2* pQ2 = (const float2*)posQ;
  const float2* pK2 = (const float2*)posK;
  const float2* pV2 = (const float2*)posV;
  float2 pq = pQ2[lane];
  uint32 qu = Q2[(size_t)n*64 + lane];
  float qx = bflo(qu) + pq.x, qy = bfhi(qu) + pq.y;
  int smp = (lane < KK) ? samples[(size_t)n*KK + lane] : 0;
  float sc[17], vx[17], vy[17];
  #pragma unroll
  for (int j=0;j<17;j++){
    int row = (j==0) ? n : __shfl(smp, j-1, 64);
    uint32 ku = K2[(size_t)row*64 + lane];
    uint32 vu = V2[(size_t)row*64 + lane];
    float2 pk = pK2[j*64 + lane];
    float2 pv = pV2[j*64 + lane];
    float kx = bflo(ku) + pk.x, ky = bfhi(ku) + pk.y;
    vx[j] = bflo(vu) + pv.x; vy[j] = bfhi(vu) + pv.y;
    float p = qx*kx + qy*ky;              // head = lane>>4 (dims 2*lane, 2*lane+1)
    p += __shfl_xor(p, 1, 64);
    p += __shfl_xor(p, 2, 64);
    p += __shfl_xor(p, 4, 64);
    p += __shfl_xor(p, 8, 64);
    sc[j] = p * 0.17677669529663687f;     // 1/sqrt(32)
  }
  float m = sc[0];
  #pragma unroll
  for (int j=1;j<17;j++) m = fmaxf(m, sc[j]);
  float ssum = 0.f;
  #pragma unroll
  for (int j=0;j<17;j++){ sc[j] = __expf(sc[j]-m); ssum += sc[j]; }
  float inv = 1.f/ssum;
  float ox=0.f, oy=0.f;
  #pragma unroll
  for (int j=0;j<17;j++){ ox += sc[j]*vx[j]; oy += sc[j]*vy[j]; }
  ((uint32*)O)[(size_t)n*64 + lane] = pack2(ox*inv, oy*inv);
}

extern "C" void kernel_launch(void* const* d_in, const int* in_sizes, int n_in,
                              void* d_out, int out_size, void* d_ws, size_t ws_size,
                              hipStream_t stream){
  const int*   adj_rows = (const int*)d_in[0];
  const int*   adj_cols = (const int*)d_in[1];
  const float* adj_vals = (const float*)d_in[2];
  const int*   samples  = (const int*)d_in[3];
  const float* user_emb = (const float*)d_in[4];
  const float* item_emb = (const float*)d_in[5];
  const float* pos_emb  = (const float*)d_in[6];
  const float* u_in_w   = (const float*)d_in[7];
  const float* u_in_b   = (const float*)d_in[8];
  const float* u_out_w  = (const float*)d_in[9];
  const float* u_out_b  = (const float*)d_in[10];
  const float* i_in_w   = (const float*)d_in[11];
  const float* i_in_b   = (const float*)d_in[12];
  const float* i_out_w  = (const float*)d_in[13];
  const float* i_out_b  = (const float*)d_in[14];
  float* out = (float*)d_out;

  char* ws = (char*)d_ws;
  size_t off = 0;
  auto alloc = [&](size_t bytes)->char*{
    char* p = ws + off; off += (bytes + 255) & ~(size_t)255; return p;
  };
  ushort_t* tmp_bf  = (ushort_t*)alloc((size_t)NN*DD*2);
  ushort_t* e_bf    = (ushort_t*)alloc((size_t)NN*DD*2);
  ushort_t* Qb      = (ushort_t*)alloc((size_t)NN*DD*2);
  ushort_t* Ku      = (ushort_t*)alloc((size_t)NN*DD*2);
  ushort_t* Vu      = (ushort_t*)alloc((size_t)NN*DD*2);
  ushort_t* Ki      = (ushort_t*)alloc((size_t)NN*DD*2);
  ushort_t* Vi      = (ushort_t*)alloc((size_t)NN*DD*2);
  ushort_t* Ob      = (ushort_t*)alloc((size_t)NN*DD*2);
  uint2*    csr     = (uint2*)   alloc((size_t)EE*8);
  int*      counts  = (int*)     alloc((size_t)NN*4);
  int*      row_ptr = (int*)     alloc((size_t)(NN+1)*4);
  int*      cursor  = (int*)     alloc((size_t)NN*4);
  int*      bsum    = (int*)     alloc(320*4);
  int*      bpre    = (int*)     alloc(320*4);
  float*    pt      = (float*)   alloc((size_t)8960*4);
  ushort_t* wbf     = (ushort_t*)alloc((size_t)131072*2);

  float* posK_u = pt;
  float* posV_u = pt + 17*128;
  float* posK_i = pt + 2*17*128;
  float* posV_i = pt + 3*17*128;
  float* posQ_u = pt + 4*17*128;
  float* posQ_i = pt + 4*17*128 + 128;

  ushort_t* wq_u = wbf;
  ushort_t* wk_u = wbf + 16384;
  ushort_t* wv_u = wbf + 2*16384;
  ushort_t* wq_i = wbf + 3*16384;
  ushort_t* wk_i = wbf + 4*16384;
  ushort_t* wv_i = wbf + 5*16384;
  ushort_t* wo_u = wbf + 6*16384;
  ushort_t* wo_i = wbf + 7*16384;

  hipMemsetAsync(counts, 0, (size_t)NN*4, stream);
  init_e_total<<<NN*DD/4/256, 256, 0, stream>>>(user_emb, item_emb, e_bf, out);
  hist_rows<<<(EE+255)/256, 256, 0, stream>>>(adj_rows, counts);
  block_sum<<<313, 256, 0, stream>>>(counts, bsum);
  scan_bsum<<<1, 512, 0, stream>>>(bsum, bpre, row_ptr);
  block_scan<<<313, 256, 0, stream>>>(counts, bpre, row_ptr, cursor);
  scatter_edges<<<(EE+255)/256, 256, 0, stream>>>(adj_rows, adj_cols, adj_vals, cursor, csr);
  pos_proj<<<dim3(17,6), 128, 0, stream>>>(pos_emb, u_in_w, u_in_b, i_in_w, i_in_b, pt);
  cvt_weights<<<512, 256, 0, stream>>>(u_in_w, i_in_w, u_out_w, i_out_w, wbf);

  for (int it = 0; it < 2; it++){
    float* tot2 = (it == 1) ? (out + (size_t)NN*DD) : nullptr;
    spmm_kernel<<<NN/4, 256, 0, stream>>>(row_ptr, csr, e_bf, tmp_bf);
    gemm16<<<NN/64, 256, 0, stream>>>(tmp_bf, wq_u, wq_i, Qb);   // Q both halves
    gemm16<<<NN/64, 256, 0, stream>>>(tmp_bf, wk_u, wk_u, Ku);
    gemm16<<<NN/64, 256, 0, stream>>>(tmp_bf, wv_u, wv_u, Vu);
    gemm16<<<NN/64, 256, 0, stream>>>(tmp_bf, wk_i, wk_i, Ki);
    gemm16<<<NN/64, 256, 0, stream>>>(tmp_bf, wv_i, wv_i, Vi);
    attn_kernel<<<USER_N/4, 256, 0, stream>>>(Qb, Ku, Vu, samples, posQ_u, posK_u, posV_u,
                                              Ob, 0, USER_N);
    attn_kernel<<<ITEM_N/4, 256, 0, stream>>>(Qb, Ki, Vi, samples, posQ_i, posK_i, posV_i,
                                              Ob, USER_N, ITEM_N);
    out_all<<<NN/64, 256, 0, stream>>>(Ob, wo_u, wo_i, u_out_b, i_out_b,
                                       tmp_bf, e_bf, out, tot2);
  }
}